// Round 1
// baseline (669.366 us; speedup 1.0000x reference)
//
#include <hip/hip_runtime.h>

// AdversarialLoss: out[b] = -(sum_c logsigmoid(pred[b,c]) - logsigmoid(pred[b,target[b]])) / C
// pred: [B=4096, C=32000] fp32, target: [B] int, out: [B] fp32.
// Memory-bound: 512 MB read -> ~81us floor at 6.3 TB/s achievable.

#define AL_B 4096
#define AL_C 32000

__device__ __forceinline__ float logsig(float x) {
    // log(sigmoid(x)) = min(x,0) - log(1 + exp(-|x|))  (numerically stable)
    float ax = fabsf(x);
    return fminf(x, 0.0f) - __logf(1.0f + __expf(-ax));
}

__global__ __launch_bounds__(256) void AdversarialLoss_kernel(
        const float* __restrict__ pred,
        const int* __restrict__ target,
        float* __restrict__ out) {
    const int b = blockIdx.x;
    const int tid = threadIdx.x;

    const float4* row = reinterpret_cast<const float4*>(pred + (size_t)b * AL_C);
    const int nvec = AL_C / 4;  // 8000 float4 per row

    float s = 0.0f;
    for (int i = tid; i < nvec; i += 256) {
        float4 v = row[i];
        s += logsig(v.x) + logsig(v.y) + logsig(v.z) + logsig(v.w);
    }

    // wave-64 butterfly reduce
    #pragma unroll
    for (int off = 32; off > 0; off >>= 1)
        s += __shfl_down(s, off, 64);

    __shared__ float ws[4];
    const int wave = tid >> 6;
    const int lane = tid & 63;
    if (lane == 0) ws[wave] = s;
    __syncthreads();

    if (tid == 0) {
        float tot = ws[0] + ws[1] + ws[2] + ws[3];
        int t = target[b];
        float tv = logsig(pred[(size_t)b * AL_C + (size_t)t]);
        out[b] = -(tot - tv) / (float)AL_C;
    }
}

extern "C" void kernel_launch(void* const* d_in, const int* in_sizes, int n_in,
                              void* d_out, int out_size, void* d_ws, size_t ws_size,
                              hipStream_t stream) {
    const float* pred  = (const float*)d_in[0];
    const int* target  = (const int*)d_in[1];
    float* out = (float*)d_out;
    AdversarialLoss_kernel<<<AL_B, 256, 0, stream>>>(pred, target, out);
}